// Round 4
// baseline (441.018 us; speedup 1.0000x reference)
//
#include <hip/hip_runtime.h>

// GraphConvolution: out[b,i,o] = relu( sum_f AX[b,i,f] * W[o,f] + bias[o] )
// AX[b,i,:] = w_i * (x[b,i-1,:] + x[b,i,:] + x[b,i+1,:]),  w_i = 1/2 ends, 1/3 interior
//
// R6: barrier-free wave-private pipeline. R3/R5 showed the block-wide barrier
// limits read duty-cycle: loads complete in ~1us, then the VMEM queue sits empty
// for the rest of each phase. Now each WAVE owns a private LDS slice (56x56 bf16
// = 6.3 KB) and a private stream of 4 batches: issue batch j+1's 13 clamped
// loads -> compute batch j from own LDS (MFMA + float4 stores; no vmcnt waits)
// -> smooth+pack+ds_write batch j+1. Within-wave DS ordering makes the single
// buffer safe (WAR); loads stay in flight across all of compute; there is NO
// __syncthreads in the kernel. 4 blocks/CU x 4 waves = 16 waves/CU, all
// independent. Numerics bit-identical to R3 (same zero-masked loads, same
// ((a+b)+c)*w order, same f2bf, same fragments) -> absmax 0.015625.

#define NODES 55
#define F 48
#define ST 56              // bf16 elems per LDS row (112 B); 16B-aligned rows
#define BPW 4              // batches per wave-stream
#define NBLK 1024          // 1024 blocks * 4 waves * 4 batches = 16384

typedef __attribute__((ext_vector_type(8))) short short8_t;
typedef __attribute__((ext_vector_type(4))) float floatx4;

__device__ __forceinline__ unsigned short f2bf(float f) {
    union { float f; unsigned int u; } v; v.f = f;
    unsigned int u = v.u;
    u += 0x7FFFu + ((u >> 16) & 1u);   // round-to-nearest-even
    return (unsigned short)(u >> 16);
}

__device__ __forceinline__ short8_t pack8(floatx4 lo, floatx4 hi) {
    short8_t r;
    r[0] = (short)f2bf(lo[0]); r[1] = (short)f2bf(lo[1]);
    r[2] = (short)f2bf(lo[2]); r[3] = (short)f2bf(lo[3]);
    r[4] = (short)f2bf(hi[0]); r[5] = (short)f2bf(hi[1]);
    r[6] = (short)f2bf(hi[2]); r[7] = (short)f2bf(hi[3]);
    return r;
}

__global__ __launch_bounds__(256, 4)
void gconv_kernel(const float* __restrict__ x, const float* __restrict__ W,
                  const float* __restrict__ bias, float* __restrict__ out) {
    __shared__ __align__(16) unsigned short s_ax[4][56 * ST];  // 25088 B total

    const int tid  = threadIdx.x;
    const int lane = tid & 63;
    const int wave = tid >> 6;
    unsigned short* sl = &s_ax[wave][0];

    // zero pad row 55 (read by clamped fragment loads; dead cols only) - wave-local
    if (lane < 14) *(uint2*)&sl[55 * ST + lane * 4] = make_uint2(0u, 0u);

    const int col  = lane & 15;    // o-index (W frag) / node-index (A frag, D col)
    const int quad = lane >> 4;    // k = quad*8 + j
    const int ko1  = 32 + (quad & 1) * 8;
    const short8_t zero8 = {0, 0, 0, 0, 0, 0, 0, 0};

    // ---- W fragments straight from global (fp32 -> bf16) [R4-verified path] ----
    short8_t wf[3][2];
#pragma unroll
    for (int nt = 0; nt < 3; ++nt) {
        const float* wr = W + (nt * 16 + col) * F;
        floatx4 w0 = *(const floatx4*)(wr + quad * 8);
        floatx4 w1 = *(const floatx4*)(wr + quad * 8 + 4);
        floatx4 w2 = *(const floatx4*)(wr + ko1);
        floatx4 w3 = *(const floatx4*)(wr + ko1 + 4);
        wf[nt][0] = pack8(w0, w1);
        short8_t t = pack8(w2, w3);
        wf[nt][1] = (quad < 2) ? t : zero8;
    }
    floatx4 bv[3];
#pragma unroll
    for (int nt = 0; nt < 3; ++nt)
        bv[nt] = *(const floatx4*)&bias[nt * 16 + quad * 4];

    // ---- staging decomposition (per wave): lane = (strip s 0..4, fq 0..11) ----
    const bool stager = lane < 60;
    const int s  = lane / 12;
    const int fq = lane - s * 12;
    const int n0 = s * 11;
    const float4* xg = reinterpret_cast<const float4*>(x);

    float4 v[13];   // staged rows n0-1 .. n0+11 (clamped, boundary-zeroed)

    const int bbase = (blockIdx.x * 4 + wave) * BPW;

    auto load_b = [&](int b) {
        if (!stager) return;
        const int base = b * 660 + fq;   // float4 index of (b, node 0, fq)
#pragma unroll
        for (int t = 0; t < 13; ++t) {
            int n  = n0 - 1 + t;
            int nc = n < 0 ? 0 : (n > 54 ? 54 : n);
            float4 tmp = xg[base + nc * 12];
            bool ok = (n >= 0) & (n <= 54);
            v[t].x = ok ? tmp.x : 0.f;
            v[t].y = ok ? tmp.y : 0.f;
            v[t].z = ok ? tmp.z : 0.f;
            v[t].w = ok ? tmp.w : 0.f;
        }
    };

    auto smooth_b = [&]() {
        if (!stager) return;
        const float ONE3 = 0.33333333333333333f;
#pragma unroll
        for (int t = 0; t < 11; ++t) {
            int n = n0 + t;
            float w = (n == 0 || n == 54) ? 0.5f : ONE3;
            float sx = (v[t].x + v[t + 1].x + v[t + 2].x) * w;
            float sy = (v[t].y + v[t + 1].y + v[t + 2].y) * w;
            float sz = (v[t].z + v[t + 1].z + v[t + 2].z) * w;
            float sw = (v[t].w + v[t + 1].w + v[t + 2].w) * w;
            unsigned int lo = (unsigned int)f2bf(sx) | ((unsigned int)f2bf(sy) << 16);
            unsigned int hi = (unsigned int)f2bf(sz) | ((unsigned int)f2bf(sw) << 16);
            *(uint2*)&sl[n * ST + fq * 4] = make_uint2(lo, hi);
        }
    };

    auto compute_b = [&](int b) {
#pragma unroll
        for (int m = 0; m < 4; ++m) {
            const int nb = m * 16 + col;            // node = D column
            const int nr = nb < 55 ? nb : 55;       // row 55 = zeros (dead cols)
            short8_t a0 = *(const short8_t*)&sl[nr * ST + quad * 8];
            short8_t t1 = *(const short8_t*)&sl[nr * ST + ko1];
            short8_t a1 = (quad < 2) ? t1 : zero8;

            floatx4 acc0 = {0.f, 0.f, 0.f, 0.f};
            floatx4 acc1 = {0.f, 0.f, 0.f, 0.f};
            floatx4 acc2 = {0.f, 0.f, 0.f, 0.f};
            acc0 = __builtin_amdgcn_mfma_f32_16x16x32_bf16(wf[0][0], a0, acc0, 0, 0, 0);
            acc1 = __builtin_amdgcn_mfma_f32_16x16x32_bf16(wf[1][0], a0, acc1, 0, 0, 0);
            acc2 = __builtin_amdgcn_mfma_f32_16x16x32_bf16(wf[2][0], a0, acc2, 0, 0, 0);
            acc0 = __builtin_amdgcn_mfma_f32_16x16x32_bf16(wf[0][1], a1, acc0, 0, 0, 0);
            acc1 = __builtin_amdgcn_mfma_f32_16x16x32_bf16(wf[1][1], a1, acc1, 0, 0, 0);
            acc2 = __builtin_amdgcn_mfma_f32_16x16x32_bf16(wf[2][1], a1, acc2, 0, 0, 0);

            // D layout: col=lane&15 (-> node), row=quad*4+j (-> o)  [m89-verified]
            if (nb < NODES) {
                float* op = out + (b * NODES + nb) * F + quad * 4;
                floatx4 v0 = acc0 + bv[0];
                floatx4 v1 = acc1 + bv[1];
                floatx4 v2 = acc2 + bv[2];
#pragma unroll
                for (int j = 0; j < 4; ++j) {
                    v0[j] = v0[j] > 0.f ? v0[j] : 0.f;
                    v1[j] = v1[j] > 0.f ? v1[j] : 0.f;
                    v2[j] = v2[j] > 0.f ? v2[j] : 0.f;
                }
                *(floatx4*)(op)      = v0;   // o = quad*4 + j
                *(floatx4*)(op + 16) = v1;
                *(floatx4*)(op + 32) = v2;
            }
        }
    };

    // ---- wave-private pipeline: loads(j+1) in flight across compute(j) ----
    load_b(bbase);
    smooth_b();
#pragma unroll
    for (int j = 0; j < BPW; ++j) {
        if (j + 1 < BPW) load_b(bbase + j + 1);
        compute_b(bbase + j);
        if (j + 1 < BPW) smooth_b();   // WAR on own slice: in-order DS, safe
    }
}

extern "C" void kernel_launch(void* const* d_in, const int* in_sizes, int n_in,
                              void* d_out, int out_size, void* d_ws, size_t ws_size,
                              hipStream_t stream) {
    const float* x    = (const float*)d_in[0];
    const float* W    = (const float*)d_in[1];
    const float* bias = (const float*)d_in[2];
    float* out = (float*)d_out;
    dim3 grid(NBLK);
    dim3 block(256);
    gconv_kernel<<<grid, block, 0, stream>>>(x, W, bias, out);
}

// Round 5
// 307.492 us; speedup vs baseline: 1.4342x; 1.4342x over previous
//
#include <hip/hip_runtime.h>

// GraphConvolution: out[b,i,o] = relu( sum_f AX[b,i,f] * W[o,f] + bias[o] )
// AX[b,i,:] = w_i * (x[b,i-1,:] + x[b,i,:] + x[b,i+1,:]),  w_i = 1/2 ends, 1/3 interior
//
// R7: R6's barrier-free wave-private pipeline, fixed for spills. R6 failed because
// launch_bounds(256,4) capped VGPRs at 64 -> v[13] spilled to scratch (+430 MB HBM
// writes, occupancy 1.4%). Now: block = 64 threads = ONE wave, private 6.3 KB LDS
// slice, stream of 8 batches. __launch_bounds__(64,2) -> 256-VGPR budget (live set
// ~160, no spill) and 8 resident blocks/CU. Pipeline per batch: issue j+1's 13
// clamped float4 loads -> compute j from own LDS (MFMA + float4 stores; v[] unused
// so no vmcnt wait) -> smooth+pack+ds_write j+1 (vmcnt wait lands here, after
// compute). No __syncthreads anywhere. 8 independent streams/CU x 13 KB in flight
// ~= 70+ KB outstanding vs ~9 KB Little's-law need for 6.3 TB/s.
// Numerics op-identical to R6 (harness-passed, absmax 0.015625).

#define NODES 55
#define F 48
#define ST 56              // bf16 elems per LDS row (112 B); 16B-aligned rows
#define BPW 8              // batches per wave-stream
#define NBLK 2048          // 2048 blocks * 1 wave * 8 batches = 16384

typedef __attribute__((ext_vector_type(8))) short short8_t;
typedef __attribute__((ext_vector_type(4))) float floatx4;

__device__ __forceinline__ unsigned short f2bf(float f) {
    union { float f; unsigned int u; } v; v.f = f;
    unsigned int u = v.u;
    u += 0x7FFFu + ((u >> 16) & 1u);   // round-to-nearest-even
    return (unsigned short)(u >> 16);
}

__device__ __forceinline__ short8_t pack8(floatx4 lo, floatx4 hi) {
    short8_t r;
    r[0] = (short)f2bf(lo[0]); r[1] = (short)f2bf(lo[1]);
    r[2] = (short)f2bf(lo[2]); r[3] = (short)f2bf(lo[3]);
    r[4] = (short)f2bf(hi[0]); r[5] = (short)f2bf(hi[1]);
    r[6] = (short)f2bf(hi[2]); r[7] = (short)f2bf(hi[3]);
    return r;
}

__global__ __launch_bounds__(64, 2)
void gconv_kernel(const float* __restrict__ x, const float* __restrict__ W,
                  const float* __restrict__ bias, float* __restrict__ out) {
    __shared__ __align__(16) unsigned short sl[56 * ST];   // 6272 B, wave-private

    const int lane = threadIdx.x;   // block = exactly one wave

    // zero pad row 55 (read by clamped fragment loads for masked cols)
    if (lane < 14) *(uint2*)&sl[55 * ST + lane * 4] = make_uint2(0u, 0u);

    const int col  = lane & 15;    // node-index within a 16-col D tile
    const int quad = lane >> 4;    // k = quad*8 + j
    const int ko1  = 32 + (quad & 1) * 8;
    const short8_t zero8 = {0, 0, 0, 0, 0, 0, 0, 0};

    // ---- W fragments straight from global (fp32 -> bf16) [R6-verified path] ----
    short8_t wf[3][2];
#pragma unroll
    for (int nt = 0; nt < 3; ++nt) {
        const float* wr = W + (nt * 16 + col) * F;
        floatx4 w0 = *(const floatx4*)(wr + quad * 8);
        floatx4 w1 = *(const floatx4*)(wr + quad * 8 + 4);
        floatx4 w2 = *(const floatx4*)(wr + ko1);
        floatx4 w3 = *(const floatx4*)(wr + ko1 + 4);
        wf[nt][0] = pack8(w0, w1);
        short8_t t = pack8(w2, w3);
        wf[nt][1] = (quad < 2) ? t : zero8;
    }
    floatx4 bv[3];
#pragma unroll
    for (int nt = 0; nt < 3; ++nt)
        bv[nt] = *(const floatx4*)&bias[nt * 16 + quad * 4];

    // ---- staging decomposition: lane = (strip s 0..4, fq 0..11), 60 active ----
    const bool stager = lane < 60;
    const int s  = lane / 12;
    const int fq = lane - s * 12;
    const int n0 = s * 11;
    const float4* xg = reinterpret_cast<const float4*>(x);

    float4 v[13];   // staged rows n0-1 .. n0+11 (clamped, boundary-zeroed)

    const int bbase = blockIdx.x * BPW;

    auto load_b = [&](int b) {
        if (!stager) return;
        const int base = b * 660 + fq;   // float4 index of (b, node 0, fq)
#pragma unroll
        for (int t = 0; t < 13; ++t) {
            int n  = n0 - 1 + t;
            int nc = n < 0 ? 0 : (n > 54 ? 54 : n);
            float4 tmp = xg[base + nc * 12];
            bool ok = (n >= 0) & (n <= 54);
            v[t].x = ok ? tmp.x : 0.f;
            v[t].y = ok ? tmp.y : 0.f;
            v[t].z = ok ? tmp.z : 0.f;
            v[t].w = ok ? tmp.w : 0.f;
        }
    };

    auto smooth_b = [&]() {
        if (!stager) return;
        const float ONE3 = 0.33333333333333333f;
#pragma unroll
        for (int t = 0; t < 11; ++t) {
            int n = n0 + t;
            float w = (n == 0 || n == 54) ? 0.5f : ONE3;
            float sx = (v[t].x + v[t + 1].x + v[t + 2].x) * w;
            float sy = (v[t].y + v[t + 1].y + v[t + 2].y) * w;
            float sz = (v[t].z + v[t + 1].z + v[t + 2].z) * w;
            float sw = (v[t].w + v[t + 1].w + v[t + 2].w) * w;
            unsigned int lo = (unsigned int)f2bf(sx) | ((unsigned int)f2bf(sy) << 16);
            unsigned int hi = (unsigned int)f2bf(sz) | ((unsigned int)f2bf(sw) << 16);
            *(uint2*)&sl[n * ST + fq * 4] = make_uint2(lo, hi);
        }
    };

    auto compute_b = [&](int b) {
#pragma unroll
        for (int m = 0; m < 4; ++m) {
            const int nb = m * 16 + col;            // node = D column
            const int nr = nb < 55 ? nb : 55;       // row 55 = zeros (masked cols)
            short8_t a0 = *(const short8_t*)&sl[nr * ST + quad * 8];
            short8_t t1 = *(const short8_t*)&sl[nr * ST + ko1];
            short8_t a1 = (quad < 2) ? t1 : zero8;

            floatx4 acc0 = {0.f, 0.f, 0.f, 0.f};
            floatx4 acc1 = {0.f, 0.f, 0.f, 0.f};
            floatx4 acc2 = {0.f, 0.f, 0.f, 0.f};
            acc0 = __builtin_amdgcn_mfma_f32_16x16x32_bf16(wf[0][0], a0, acc0, 0, 0, 0);
            acc1 = __builtin_amdgcn_mfma_f32_16x16x32_bf16(wf[1][0], a0, acc1, 0, 0, 0);
            acc2 = __builtin_amdgcn_mfma_f32_16x16x32_bf16(wf[2][0], a0, acc2, 0, 0, 0);
            acc0 = __builtin_amdgcn_mfma_f32_16x16x32_bf16(wf[0][1], a1, acc0, 0, 0, 0);
            acc1 = __builtin_amdgcn_mfma_f32_16x16x32_bf16(wf[1][1], a1, acc1, 0, 0, 0);
            acc2 = __builtin_amdgcn_mfma_f32_16x16x32_bf16(wf[2][1], a1, acc2, 0, 0, 0);

            // D layout: col=lane&15 (-> node), row=quad*4+j (-> o)  [m89-verified]
            if (nb < NODES) {
                float* op = out + (b * NODES + nb) * F + quad * 4;
                floatx4 v0 = acc0 + bv[0];
                floatx4 v1 = acc1 + bv[1];
                floatx4 v2 = acc2 + bv[2];
#pragma unroll
                for (int j = 0; j < 4; ++j) {
                    v0[j] = v0[j] > 0.f ? v0[j] : 0.f;
                    v1[j] = v1[j] > 0.f ? v1[j] : 0.f;
                    v2[j] = v2[j] > 0.f ? v2[j] : 0.f;
                }
                *(floatx4*)(op)      = v0;   // o = quad*4 + j
                *(floatx4*)(op + 16) = v1;
                *(floatx4*)(op + 32) = v2;
            }
        }
    };

    // ---- wave-private pipeline: loads(j+1) in flight across compute(j) ----
    load_b(bbase);
    smooth_b();
    for (int j = 0; j < BPW; ++j) {
        if (j + 1 < BPW) load_b(bbase + j + 1);
        compute_b(bbase + j);
        if (j + 1 < BPW) smooth_b();   // WAR on own slice: in-order DS, safe
    }
}

extern "C" void kernel_launch(void* const* d_in, const int* in_sizes, int n_in,
                              void* d_out, int out_size, void* d_ws, size_t ws_size,
                              hipStream_t stream) {
    const float* x    = (const float*)d_in[0];
    const float* W    = (const float*)d_in[1];
    const float* bias = (const float*)d_in[2];
    float* out = (float*)d_out;
    dim3 grid(NBLK);
    dim3 block(64);
    gconv_kernel<<<grid, block, 0, stream>>>(x, W, bias, out);
}